// Round 5
// baseline (34.489 us; speedup 1.0000x reference)
//
#include <hip/hip_runtime.h>

#define H 4096
#define BLOCK 256
#define PER_THREAD (H / BLOCK)   // 16 floats/thread
#define VECS (PER_THREAD / 4)    // 4 float4 per thread

__global__ __launch_bounds__(BLOCK) void quant_int4_kernel(
    const float* __restrict__ x,
    float* __restrict__ out_packed,   // packed int8 values, stored as float
    float* __restrict__ out_scales,   // per-row scales
    float r7)                         // fl32(1/7), host-computed
{
    const int row = blockIdx.x;
    const int t = threadIdx.x;
    const float4* xr = reinterpret_cast<const float4*>(x + (size_t)row * H);

    // ---- load row into registers (coalesced float4), per-thread absmax ----
    float4 v[VECS];
    float m = 0.0f;
#pragma unroll
    for (int j = 0; j < VECS; ++j) {
        v[j] = xr[t + BLOCK * j];
        m = fmaxf(m, fmaxf(fmaxf(fabsf(v[j].x), fabsf(v[j].y)),
                           fmaxf(fabsf(v[j].z), fabsf(v[j].w))));
    }

    // ---- wave64 butterfly max-reduce (exact) ----
#pragma unroll
    for (int off = 32; off > 0; off >>= 1)
        m = fmaxf(m, __shfl_xor(m, off, 64));

    // ---- cross-wave reduce via LDS, broadcast row absmax ----
    __shared__ float smax[BLOCK / 64];
    const int wave = t >> 6;
    if ((t & 63) == 0) smax[wave] = m;
    __syncthreads();
    if (t == 0) {
        float mm = smax[0];
#pragma unroll
        for (int w = 1; w < BLOCK / 64; ++w) mm = fmaxf(mm, smax[w]);
        smax[0] = mm;
    }
    __syncthreads();
    const float absmax = smax[0];

    // ---- XLA-style scale: s = fl32( fl32(absmax*0.9f) * fl32(1/7) ) ----
    // XLA rewrites /7 into *(1/7); replicate that exactly. The asm barrier
    // stops fast-math from folding 0.9f*r7 into a single constant.
    float tt = absmax * 0.9f;          // exact single f32 op
    asm volatile("" : "+v"(tt));
    float s = tt * r7;                 // exact single f32 op
    s = fmaxf(s, 1e-8f);

    // ---- inv = 1/s in f64, Newton-refined; (f32)((f64)x*inv) == fl32(x/s)
    // exactly (quotient never an f32 midpoint; err 2^-51 << 2^-48 gap). ----
    double s64 = (double)s;
    asm volatile("" : "+v"(s64));
    double inv = 1.0 / s64;
    inv = inv * (2.0 - s64 * inv);     // NR -> ~0.5 ulp f64
    asm volatile("" : "+v"(inv));

    // ---- quantize RNE, clip, pack two int4/byte, write coalesced float2 ----
    float2* outp = reinterpret_cast<float2*>(out_packed + (size_t)row * (H / 2));
#pragma unroll
    for (int j = 0; j < VECS; ++j) {
        float qf0 = (float)((double)v[j].x * inv);
        float qf1 = (float)((double)v[j].y * inv);
        float qf2 = (float)((double)v[j].z * inv);
        float qf3 = (float)((double)v[j].w * inv);
        int q0 = (int)rintf(qf0); q0 = max(-8, min(7, q0));
        int q1 = (int)rintf(qf1); q1 = max(-8, min(7, q1));
        int q2 = (int)rintf(qf2); q2 = max(-8, min(7, q2));
        int q3 = (int)rintf(qf3); q3 = max(-8, min(7, q3));
        int b0 = ((q1 & 0xF) << 4) | (q0 & 0xF);   // elem1 -> high nibble
        int b1 = ((q3 & 0xF) << 4) | (q2 & 0xF);
        float f0 = (float)(signed char)(b0 & 0xFF); // value of the packed int8
        float f1 = (float)(signed char)(b1 & 0xFF);
        outp[t + BLOCK * j] = make_float2(f0, f1);
    }

    if (t == 0) out_scales[row] = s;
}

extern "C" void kernel_launch(void* const* d_in, const int* in_sizes, int n_in,
                              void* d_out, int out_size, void* d_ws, size_t ws_size,
                              hipStream_t stream) {
    const float* x = (const float*)d_in[0];
    const int n = in_sizes[0];          // 4*2048*4096
    const int rows = n / H;             // 8192
    float* out = (float*)d_out;
    float* out_packed = out;            // n/2 packed values (as float)
    float* out_scales = out + (size_t)n / 2;  // rows scales

    const float r7 = 1.0f / 7.0f;       // host/compile-time fold: fl32(1/7)
    quant_int4_kernel<<<rows, BLOCK, 0, stream>>>(x, out_packed, out_scales, r7);
}